// Round 15
// baseline (1929.928 us; speedup 1.0000x reference)
//
#include <hip/hip_runtime.h>
#include <stdint.h>

// GeneDynamics: out = -x + (A @ x^2) / (x^2 + 1)
// v11: zero-LDS zero-barrier row streaming. Wave owns 4 full rows; A read as
//      4 KB back-to-back contiguous bursts per row (DRAM page locality);
//      xh^T read per-d as 1 KB wave-contiguous L2-hit loads (never DRAM).
//      32 accs/thread (no spill), 63-shfl butterfly, non-atomic stores.

#define NN 16384
#define DIM 16
#define TPB 256                 // 4 waves/block
#define GRID 1024               // 4096 waves x 4 rows = 16384 rows

// prep: xhT[d][i] = x[i][d]^2   (transposed; per-d stores are lane-coalesced)
__global__ __launch_bounds__(256) void prep_kernel(const float* __restrict__ x,
                                                   float* __restrict__ xhT) {
    int i = blockIdx.x * 256 + threadIdx.x;            // row 0..16383
    const float4* xr = reinterpret_cast<const float4*>(x + (size_t)i * DIM);
    #pragma unroll
    for (int v = 0; v < 4; ++v) {
        float4 xv = xr[v];
        xhT[(size_t)(4 * v + 0) * NN + i] = xv.x * xv.x;
        xhT[(size_t)(4 * v + 1) * NN + i] = xv.y * xv.y;
        xhT[(size_t)(4 * v + 2) * NN + i] = xv.z * xv.z;
        xhT[(size_t)(4 * v + 3) * NN + i] = xv.w * xv.w;
    }
}

__global__ __launch_bounds__(TPB, 4) void agg_kernel(const float* __restrict__ A,
                                                     const float* __restrict__ xhT,
                                                     const float* __restrict__ x,
                                                     float* __restrict__ out) {
    const int tid = threadIdx.x;
    const int l = tid & 63, w = tid >> 6;
    const int gw = blockIdx.x * 4 + w;     // global wave id
    const int r0 = gw * 4;                 // wave's 4 rows

    #pragma unroll
    for (int rp = 0; rp < 2; ++rp) {
        const int rA = r0 + rp * 2;
        const float* __restrict__ pA = A + (size_t)rA * NN + 4 * l;
        const float* __restrict__ pB = pA + NN;        // row rA+1

        float acc0[16], acc1[16];
        #pragma unroll
        for (int d = 0; d < 16; ++d) { acc0[d] = 0.f; acc1[d] = 0.f; }

        for (int wk = 0; wk < 16; ++wk) {              // 1024-k windows
            const int kb = wk * 1024;
            // ---- row A: one 4 KB back-to-back contiguous burst ----
            float4 a0[4];
            #pragma unroll
            for (int c = 0; c < 4; ++c)
                a0[c] = *reinterpret_cast<const float4*>(pA + kb + c * 256);
            #pragma unroll
            for (int c = 0; c < 4; ++c) {
                const float* xb = xhT + kb + c * 256 + 4 * l;
                #pragma unroll
                for (int d = 0; d < 16; ++d) {
                    float4 q = *reinterpret_cast<const float4*>(xb + (size_t)d * NN);
                    acc0[d] += a0[c].x * q.x + a0[c].y * q.y +
                               a0[c].z * q.z + a0[c].w * q.w;
                }
            }
            // ---- row B: 4 KB burst; xh re-read (L2-hot, never DRAM) ----
            float4 a1[4];
            #pragma unroll
            for (int c = 0; c < 4; ++c)
                a1[c] = *reinterpret_cast<const float4*>(pB + kb + c * 256);
            #pragma unroll
            for (int c = 0; c < 4; ++c) {
                const float* xb = xhT + kb + c * 256 + 4 * l;
                #pragma unroll
                for (int d = 0; d < 16; ++d) {
                    float4 q = *reinterpret_cast<const float4*>(xb + (size_t)d * NN);
                    acc1[d] += a1[c].x * q.x + a1[c].y * q.y +
                               a1[c].z * q.z + a1[c].w * q.w;
                }
            }
        }

        // ---- butterfly: lane ell ends with output idx (ell&31) = (row<<4)|d ----
        float val[32];
        #pragma unroll
        for (int d = 0; d < 16; ++d) { val[d] = acc0[d]; val[16 + d] = acc1[d]; }

        const int b4 = (l >> 4) & 1, b3 = (l >> 3) & 1, b2 = (l >> 2) & 1,
                  b1 = (l >> 1) & 1, b0 = l & 1;
        #pragma unroll
        for (int i = 0; i < 32; ++i) val[i] += __shfl_xor(val[i], 32);
        #pragma unroll
        for (int i = 0; i < 16; ++i) {
            float send = b4 ? val[i] : val[i + 16];
            float keep = b4 ? val[i + 16] : val[i];
            val[i] = keep + __shfl_xor(send, 16);
        }
        #pragma unroll
        for (int i = 0; i < 8; ++i) {
            float send = b3 ? val[i] : val[i + 8];
            float keep = b3 ? val[i + 8] : val[i];
            val[i] = keep + __shfl_xor(send, 8);
        }
        #pragma unroll
        for (int i = 0; i < 4; ++i) {
            float send = b2 ? val[i] : val[i + 4];
            float keep = b2 ? val[i + 4] : val[i];
            val[i] = keep + __shfl_xor(send, 4);
        }
        #pragma unroll
        for (int i = 0; i < 2; ++i) {
            float send = b1 ? val[i] : val[i + 2];
            float keep = b1 ? val[i + 2] : val[i];
            val[i] = keep + __shfl_xor(send, 2);
        }
        {
            float send = b0 ? val[0] : val[1];
            float keep = b0 ? val[1] : val[0];
            val[0] = keep + __shfl_xor(send, 1);
        }

        // ---- fused epilogue, non-atomic (wave exclusively owns its rows) ----
        if (l < 32) {
            const size_t o = (size_t)rA * DIM + l;     // = (rA + (l>>4))*16 + (l&15)
            float xv = x[o];
            out[o] = -xv + val[0] / (xv * xv + 1.0f);
        }
    }
}

extern "C" void kernel_launch(void* const* d_in, const int* in_sizes, int n_in,
                              void* d_out, int out_size, void* d_ws, size_t ws_size,
                              hipStream_t stream) {
    const float* A = (const float*)d_in[0];
    const float* x = (const float*)d_in[1];
    float* out = (float*)d_out;
    float* xhT = (float*)d_ws;                      // 1 MiB  [16][16384]

    prep_kernel<<<NN / 256, 256, 0, stream>>>(x, xhT);
    agg_kernel<<<GRID, TPB, 0, stream>>>(A, xhT, x, out);
}

// Round 16
// 512.607 us; speedup vs baseline: 3.7649x; 3.7649x over previous
//
#include <hip/hip_runtime.h>
#include <stdint.h>

// GeneDynamics: out = -x + (A @ x^2) / (x^2 + 1)
// v12: m13-copy-pattern read test, spill-proofed. Wave owns 2 consecutive
//      rows (128 KB linear stream), no K-split/LDS/barriers. xhT reads are
//      L1/L2-hot wave-contiguous. amdgpu_waves_per_eu(2,4) gives the
//      allocator a 128-VGPR budget so it cannot spill-chase occupancy 8.

#define NN 16384
#define DIM 16
#define TPB 256                 // 4 waves/block
#define RPW 2                   // rows per wave
#define GRID (NN / (RPW * 4))   // 2048 blocks

// prep: xhT[d][i] = x[i][d]^2   (transposed; per-d stores are lane-coalesced)
__global__ __launch_bounds__(256) void prep_kernel(const float* __restrict__ x,
                                                   float* __restrict__ xhT) {
    int i = blockIdx.x * 256 + threadIdx.x;            // row 0..16383
    const float4* xr = reinterpret_cast<const float4*>(x + (size_t)i * DIM);
    #pragma unroll
    for (int v = 0; v < 4; ++v) {
        float4 xv = xr[v];
        xhT[(size_t)(4 * v + 0) * NN + i] = xv.x * xv.x;
        xhT[(size_t)(4 * v + 1) * NN + i] = xv.y * xv.y;
        xhT[(size_t)(4 * v + 2) * NN + i] = xv.z * xv.z;
        xhT[(size_t)(4 * v + 3) * NN + i] = xv.w * xv.w;
    }
}

__global__ __launch_bounds__(TPB)
__attribute__((amdgpu_waves_per_eu(2, 4)))
void agg_kernel(const float* __restrict__ A,
                const float* __restrict__ xhT,
                const float* __restrict__ x,
                float* __restrict__ out) {
    const int tid = threadIdx.x;
    const int l = tid & 63, w = tid >> 6;
    const int gw = blockIdx.x * 4 + w;     // global wave id
    const int r0 = gw * RPW;               // wave's 2 consecutive rows

    const float* __restrict__ pA = A + (size_t)r0 * NN + 4 * l;
    const float* __restrict__ pB = pA + NN;

    float acc0[16], acc1[16];
    #pragma unroll
    for (int d = 0; d < 16; ++d) { acc0[d] = 0.f; acc1[d] = 0.f; }

    // 64 windows x 256 floats: wave address stream over A is PERFECTLY LINEAR
    // (rows r0, r0+1 are adjacent in memory -> one 128 KB run).
    for (int wk = 0; wk < NN / 256; ++wk) {
        const int base = wk * 256;
        float4 a0 = *reinterpret_cast<const float4*>(pA + base);
        float4 a1 = *reinterpret_cast<const float4*>(pB + base);
        const float* xb = xhT + base + 4 * l;
        #pragma unroll
        for (int d = 0; d < 16; ++d) {
            float4 q = *reinterpret_cast<const float4*>(xb + (size_t)d * NN);
            acc0[d] += a0.x * q.x + a0.y * q.y + a0.z * q.z + a0.w * q.w;
            acc1[d] += a1.x * q.x + a1.y * q.y + a1.z * q.z + a1.w * q.w;
        }
    }

    // ---- butterfly: 32 outputs (2 rows x 16 d) distributed to lanes 0..31 ----
    float val[32];
    #pragma unroll
    for (int d = 0; d < 16; ++d) { val[d] = acc0[d]; val[16 + d] = acc1[d]; }

    const int b4 = (l >> 4) & 1, b3 = (l >> 3) & 1, b2 = (l >> 2) & 1,
              b1 = (l >> 1) & 1, b0 = l & 1;
    #pragma unroll
    for (int i = 0; i < 32; ++i) val[i] += __shfl_xor(val[i], 32);
    #pragma unroll
    for (int i = 0; i < 16; ++i) {
        float send = b4 ? val[i] : val[i + 16];
        float keep = b4 ? val[i + 16] : val[i];
        val[i] = keep + __shfl_xor(send, 16);
    }
    #pragma unroll
    for (int i = 0; i < 8; ++i) {
        float send = b3 ? val[i] : val[i + 8];
        float keep = b3 ? val[i + 8] : val[i];
        val[i] = keep + __shfl_xor(send, 8);
    }
    #pragma unroll
    for (int i = 0; i < 4; ++i) {
        float send = b2 ? val[i] : val[i + 4];
        float keep = b2 ? val[i + 4] : val[i];
        val[i] = keep + __shfl_xor(send, 4);
    }
    #pragma unroll
    for (int i = 0; i < 2; ++i) {
        float send = b1 ? val[i] : val[i + 2];
        float keep = b1 ? val[i + 2] : val[i];
        val[i] = keep + __shfl_xor(send, 2);
    }
    {
        float send = b0 ? val[0] : val[1];
        float keep = b0 ? val[1] : val[0];
        val[0] = keep + __shfl_xor(send, 1);
    }

    // ---- fused epilogue, non-atomic (wave exclusively owns its 2 rows) ----
    if (l < 32) {
        const size_t o = (size_t)r0 * DIM + l;   // row r0+(l>>4), dim l&15
        float xv = x[o];
        out[o] = -xv + val[0] / (xv * xv + 1.0f);
    }
}

extern "C" void kernel_launch(void* const* d_in, const int* in_sizes, int n_in,
                              void* d_out, int out_size, void* d_ws, size_t ws_size,
                              hipStream_t stream) {
    const float* A = (const float*)d_in[0];
    const float* x = (const float*)d_in[1];
    float* out = (float*)d_out;
    float* xhT = (float*)d_ws;                      // 1 MiB  [16][16384]

    prep_kernel<<<NN / 256, 256, 0, stream>>>(x, xhT);
    agg_kernel<<<GRID, TPB, 0, stream>>>(A, xhT, x, out);
}

// Round 17
// 296.099 us; speedup vs baseline: 6.5178x; 1.7312x over previous
//
#include <hip/hip_runtime.h>
#include <stdint.h>

// GeneDynamics: out = -x + (A @ x^2) / (x^2 + 1)
// v13: v9 structure (1 KiB-contiguous global_load_lds staging, single-buffer
//      2-phase) with ROWS=32 -> 48 KiB LDS -> 3 blocks/CU (better issue duty
//      cycle during drains) + NT cache policy (aux=2) on stream-once A loads.

#define NN 16384
#define DIM 16
#define TPB 256                // 4 waves
#define ROWS 32                // rows per block
#define NRB 512                // NN / ROWS
#define KSPLIT 2
#define KRANGE 8192            // NN / KSPLIT
#define KC 256                 // k per chunk (1 KiB per row per chunk)
#define NCH 32                 // KRANGE / KC

// prep: out = -x ; xh = x^2 ; inv = 1/(x^2+1)
__global__ __launch_bounds__(256) void prep_kernel(const float* __restrict__ x,
                                                   float* __restrict__ out,
                                                   float* __restrict__ xh,
                                                   float* __restrict__ inv) {
    int i = blockIdx.x * 256 + threadIdx.x;            // 65536 float4s
    float4 v = reinterpret_cast<const float4*>(x)[i];
    reinterpret_cast<float4*>(out)[i] = make_float4(-v.x, -v.y, -v.z, -v.w);
    float4 h = make_float4(v.x * v.x, v.y * v.y, v.z * v.z, v.w * v.w);
    reinterpret_cast<float4*>(xh)[i] = h;
    reinterpret_cast<float4*>(inv)[i] =
        make_float4(1.0f / (h.x + 1.0f), 1.0f / (h.y + 1.0f),
                    1.0f / (h.z + 1.0f), 1.0f / (h.w + 1.0f));
}

__device__ __forceinline__ void gload_lds16(const float* g, float* l, int aux) {
    if (aux)
        __builtin_amdgcn_global_load_lds(
            (const __attribute__((address_space(1))) void*)g,
            (__attribute__((address_space(3))) void*)l, 16, 0, 2 /*NT*/);
    else
        __builtin_amdgcn_global_load_lds(
            (const __attribute__((address_space(1))) void*)g,
            (__attribute__((address_space(3))) void*)l, 16, 0, 0);
}

__global__ __launch_bounds__(TPB) void agg_kernel(const float* __restrict__ A,
                                                  const float* __restrict__ xh,
                                                  const float* __restrict__ inv,
                                                  float* __restrict__ out) {
    // tA[32 rows][256 k]: row r holds logical f4-slot s at phys s^(r&7)
    //   (involution carried on the per-lane SOURCE address; dest lane-linear).
    // tX[256 k][16 d]: k's d-f4-slot v stored at phys v^((k>>4)&3).
    __shared__ float tA[ROWS * KC];   // 32 KiB
    __shared__ float tX[KC * DIM];    // 16 KiB   (48 KiB total -> 3 blocks/CU)

    const int tid = threadIdx.x;
    const int l = tid & 63, w = tid >> 6, m = l & 15, q = l >> 4;
    const int rb = blockIdx.x & (NRB - 1);
    const int ks = blockIdx.x >> 9;
    const int r0 = rb * ROWS;
    const size_t k0 = (size_t)ks * KRANGE;

    // ---- A staging: wave w, instr i -> row 8w+i; lane l loads logical
    //      f4-slot l^(i&7) of that row's 1 KiB chunk segment (contiguous span)
    const float* Ab = A + (size_t)(r0 + 8 * w) * NN + k0;
    int aoff[8];
    #pragma unroll
    for (int i = 0; i < 8; ++i) aoff[i] = 4 * (l ^ (i & 7));

    // ---- X staging: instr j covers phys f4-slots (4w+j)*64 + l ----
    const float* Xc = xh + k0 * DIM;
    int xoff[4];
    #pragma unroll
    for (int j = 0; j < 4; ++j)
        xoff[j] = (((4 * w + j) * 16 + (l >> 2)) << 4) + 4 * ((l & 3) ^ j);

    // ---- compute-side read indices (loop-invariant) ----
    // thread (w,q,m): rows m+16j (j=0,1), k_loc = 64w+16q+4b+e
    int rA[2][4];
    #pragma unroll
    for (int j = 0; j < 2; ++j)
        #pragma unroll
        for (int b = 0; b < 4; ++b)
            rA[j][b] = (m + 16 * j) * KC + 4 * ((16 * w + 4 * q + b) ^ (m & 7));
    int rX[4];
    #pragma unroll
    for (int v = 0; v < 4; ++v)
        rX[v] = (64 * w + 16 * q) * 16 + 4 * (v ^ ((4 * w + q) & 3));

    float4 acc[2][4];   // [row j][d-slot v]  (32 floats -> no spill risk)
    #pragma unroll
    for (int j = 0; j < 2; ++j)
        #pragma unroll
        for (int v = 0; v < 4; ++v) acc[j][v] = make_float4(0.f, 0.f, 0.f, 0.f);

    for (int t = 0; t < NCH; ++t) {
        __syncthreads();                 // tile t-1 fully consumed by all waves
        // ---- STAGE(t): 8 A-instrs (1 KiB contiguous, NT) + 4 X-instrs ----
        {
            const float* sA = Ab + (size_t)t * KC;
            #pragma unroll
            for (int i = 0; i < 8; ++i)
                gload_lds16(sA + (size_t)i * NN + aoff[i],
                            &tA[(8 * w + i) * KC], 1);
            const float* sX = Xc + (size_t)t * (KC * DIM);
            #pragma unroll
            for (int j = 0; j < 4; ++j)
                gload_lds16(sX + xoff[j], &tX[(4 * w + j) * 256], 0);
        }
        __syncthreads();                 // vmcnt(0) drain: tile t resident
        // ---- COMPUTE(t): LDS-only reads + FMA ----
        #pragma unroll
        for (int b = 0; b < 4; ++b) {
            float4 ar[2];
            ar[0] = *reinterpret_cast<const float4*>(&tA[rA[0][b]]);
            ar[1] = *reinterpret_cast<const float4*>(&tA[rA[1][b]]);
            #pragma unroll
            for (int e = 0; e < 4; ++e) {
                float4 xv[4];
                #pragma unroll
                for (int v = 0; v < 4; ++v)
                    xv[v] = *reinterpret_cast<const float4*>(
                        &tX[rX[v] + (4 * b + e) * 16]);
                #pragma unroll
                for (int j = 0; j < 2; ++j) {
                    const float a = (&ar[j].x)[e];         // e unrolled -> static
                    #pragma unroll
                    for (int v = 0; v < 4; ++v) {
                        acc[j][v].x += a * xv[v].x;
                        acc[j][v].y += a * xv[v].y;
                        acc[j][v].z += a * xv[v].z;
                        acc[j][v].w += a * xv[v].w;
                    }
                }
            }
        }
    }

    // ---- merge the 4 k-phases q (lane bits 4,5) ----
    #pragma unroll
    for (int j = 0; j < 2; ++j)
        #pragma unroll
        for (int v = 0; v < 4; ++v) {
            acc[j][v].x += __shfl_xor(acc[j][v].x, 16);
            acc[j][v].y += __shfl_xor(acc[j][v].y, 16);
            acc[j][v].z += __shfl_xor(acc[j][v].z, 16);
            acc[j][v].w += __shfl_xor(acc[j][v].w, 16);
            acc[j][v].x += __shfl_xor(acc[j][v].x, 32);
            acc[j][v].y += __shfl_xor(acc[j][v].y, 32);
            acc[j][v].z += __shfl_xor(acc[j][v].z, 32);
            acc[j][v].w += __shfl_xor(acc[j][v].w, 32);
        }

    // q==0 lanes write rows m+16j; waves + KSPLIT merge via atomics
    // (epilogue is linear in agg -> split-K exact)
    if (q == 0) {
        #pragma unroll
        for (int j = 0; j < 2; ++j) {
            const int R = r0 + m + 16 * j;
            const float4* iv4 = reinterpret_cast<const float4*>(inv + (size_t)R * DIM);
            float* orow = out + (size_t)R * DIM;
            #pragma unroll
            for (int v = 0; v < 4; ++v) {
                float4 iv = iv4[v];
                atomicAdd(&orow[4 * v + 0], acc[j][v].x * iv.x);
                atomicAdd(&orow[4 * v + 1], acc[j][v].y * iv.y);
                atomicAdd(&orow[4 * v + 2], acc[j][v].z * iv.z);
                atomicAdd(&orow[4 * v + 3], acc[j][v].w * iv.w);
            }
        }
    }
}

extern "C" void kernel_launch(void* const* d_in, const int* in_sizes, int n_in,
                              void* d_out, int out_size, void* d_ws, size_t ws_size,
                              hipStream_t stream) {
    const float* A = (const float*)d_in[0];
    const float* x = (const float*)d_in[1];
    float* out = (float*)d_out;
    float* xhp = (float*)d_ws;                      // 1 MiB
    float* inv = (float*)d_ws + (size_t)NN * DIM;   // 1 MiB

    prep_kernel<<<(NN * DIM / 4) / 256, 256, 0, stream>>>(x, out, xhp, inv);
    agg_kernel<<<NRB * KSPLIT, TPB, 0, stream>>>(A, xhp, inv, out);
}